// Round 4
// baseline (248.550 us; speedup 1.0000x reference)
//
#include <hip/hip_runtime.h>
#include <hip/hip_bf16.h>

#define NTOK 8192
#define DIN  1024
#define HID  2048
#define OUTD 1024
#define NEXP 8
#define BM 128
#define BN 128
#define BK 64
#define MAXTILES (NTOK / BM + NEXP)   // 72
#define LDSZ (BM * BK)                // shorts per operand buffer (8192)

typedef short short8 __attribute__((ext_vector_type(8)));
typedef float f32x4 __attribute__((ext_vector_type(4)));

static __device__ __forceinline__ unsigned short f2bf(float f) {
  union { __hip_bfloat16 b; unsigned short u; } cv;
  cv.b = __float2bfloat16(f);
  return cv.u;
}

static __device__ __forceinline__ void gload_lds16(const void* g, void* l) {
  __builtin_amdgcn_global_load_lds(
      (const __attribute__((address_space(1))) void*)g,
      (__attribute__((address_space(3))) void*)l, 16, 0, 0);
}

// ---------------- prep: W [E][R][C] fp32 -> WT [E][C][R] bf16 ----------------
// 64x64 tiles, float4 loads / ushort4 stores.
__global__ __launch_bounds__(256) void transpose_convert_kernel(
    const float* __restrict__ W, unsigned short* __restrict__ WT, int R, int C) {
  __shared__ float tile[64][65];
  const int e = blockIdx.z;
  const int c0 = blockIdx.x * 64, r0 = blockIdx.y * 64;
  const int lr = threadIdx.x >> 4;    // 0..15
  const int fc = threadIdx.x & 15;    // float4 column
  const float* Wp = W + ((size_t)e * R + r0) * C + c0;
#pragma unroll
  for (int i = 0; i < 4; ++i) {
    int r = lr + i * 16;
    float4 v = *(const float4*)(Wp + (size_t)r * C + fc * 4);
    tile[r][fc * 4 + 0] = v.x; tile[r][fc * 4 + 1] = v.y;
    tile[r][fc * 4 + 2] = v.z; tile[r][fc * 4 + 3] = v.w;
  }
  __syncthreads();
  unsigned short* Op = WT + ((size_t)e * C + c0) * R + r0;
#pragma unroll
  for (int i = 0; i < 4; ++i) {
    int cc = lr + i * 16;             // output row = source col
    int rb = fc * 4;                  // 4 source rows
    ushort4 o = { f2bf(tile[rb + 0][cc]), f2bf(tile[rb + 1][cc]),
                  f2bf(tile[rb + 2][cc]), f2bf(tile[rb + 3][cc]) };
    *(ushort4*)(Op + (size_t)cc * R + rb) = o;
  }
}

// ---------------- fused: x fp32 -> bf16  +  router (fp32, NO atomics) ------
__global__ __launch_bounds__(256) void fused_router_kernel(
    const float* __restrict__ x, const float* __restrict__ Wr,
    const float* __restrict__ br, unsigned short* __restrict__ xb,
    float* __restrict__ probs_out, int* __restrict__ routes) {
  __shared__ float WrL[NEXP][DIN];   // transposed router weights, 32 KB
  const int tid = threadIdx.x;
#pragma unroll
  for (int rr = 0; rr < 4; ++rr) {
    int row = tid * 4 + rr;
    float4 w0 = *(const float4*)(Wr + (size_t)row * NEXP);
    float4 w1 = *(const float4*)(Wr + (size_t)row * NEXP + 4);
    WrL[0][row] = w0.x; WrL[1][row] = w0.y; WrL[2][row] = w0.z; WrL[3][row] = w0.w;
    WrL[4][row] = w1.x; WrL[5][row] = w1.y; WrL[6][row] = w1.z; WrL[7][row] = w1.w;
  }
  __syncthreads();

  const int lane = tid & 63;
  const int n = blockIdx.x * 4 + (tid >> 6);
  const float4* xr = (const float4*)(x + (size_t)n * DIN);
  ushort4* xo = (ushort4*)(xb + (size_t)n * DIN);
  float acc[NEXP];
#pragma unroll
  for (int e = 0; e < NEXP; ++e) acc[e] = 0.f;
#pragma unroll
  for (int j = 0; j < 4; ++j) {
    int idx = j * 64 + lane;            // coalesced: 64 consecutive float4
    float4 xv = xr[idx];
    ushort4 o = { f2bf(xv.x), f2bf(xv.y), f2bf(xv.z), f2bf(xv.w) };
    xo[idx] = o;
    int r0 = idx * 4;
#pragma unroll
    for (int e = 0; e < NEXP; ++e) {
      float4 wv = *(const float4*)&WrL[e][r0];
      acc[e] += xv.x * wv.x + xv.y * wv.y + xv.z * wv.z + xv.w * wv.w;
    }
  }
#pragma unroll
  for (int m = 1; m < 64; m <<= 1)
#pragma unroll
    for (int e = 0; e < NEXP; ++e) acc[e] += __shfl_xor(acc[e], m);

  if (lane == 0) {
    float lg[NEXP], p[NEXP];
    float mx = -1e30f;
#pragma unroll
    for (int e = 0; e < NEXP; ++e) { lg[e] = acc[e] + br[e]; mx = fmaxf(mx, lg[e]); }
    float s = 0.f;
#pragma unroll
    for (int e = 0; e < NEXP; ++e) { p[e] = expf(lg[e] - mx); s += p[e]; }
    float inv = 1.f / s;
    int best = 0; float bp = -1.f;
#pragma unroll
    for (int e = 0; e < NEXP; ++e) {
      p[e] *= inv;
      probs_out[(size_t)n * NEXP + e] = p[e];
      if (p[e] > bp) { bp = p[e]; best = e; }   // strict > : first-index tie-break
    }
    routes[n] = best;
  }
}

// ---------------- histogram + scan (single block, no atomics) ----------------
__global__ __launch_bounds__(256) void hist_scan_kernel(
    const int* __restrict__ routes, int* __restrict__ pad_off,
    int2* __restrict__ tile_table, float* __restrict__ counts_out) {
  __shared__ int wsum[4][NEXP];
  const int tid = threadIdx.x;
  const int lane = tid & 63, w = tid >> 6;
  int cnt[NEXP];
#pragma unroll
  for (int e = 0; e < NEXP; ++e) cnt[e] = 0;
#pragma unroll
  for (int j = 0; j < 8; ++j) {
    int4 r4 = ((const int4*)routes)[tid + 256 * j];
    int rr[4] = {r4.x, r4.y, r4.z, r4.w};
#pragma unroll
    for (int i = 0; i < 4; ++i)
#pragma unroll
      for (int e = 0; e < NEXP; ++e) cnt[e] += (rr[i] == e);  // no runtime idx -> regs
  }
#pragma unroll
  for (int m = 1; m < 64; m <<= 1)
#pragma unroll
    for (int e = 0; e < NEXP; ++e) cnt[e] += __shfl_xor(cnt[e], m);
  if (lane == 0)
#pragma unroll
    for (int e = 0; e < NEXP; ++e) wsum[w][e] = cnt[e];
  __syncthreads();
  if (tid == 0) {
    int off = 0, t = 0;
    for (int e = 0; e < NEXP; ++e) {
      int c = wsum[0][e] + wsum[1][e] + wsum[2][e] + wsum[3][e];
      pad_off[e] = off;
      counts_out[e] = (float)c;
      int tiles = (c + BM - 1) / BM;
      for (int i = 0; i < tiles; ++i) { tile_table[t] = make_int2(e, off + i * BM); ++t; }
      off += tiles * BM;
    }
    for (; t < MAXTILES; ++t) tile_table[t] = make_int2(-1, 0);
  }
}

// ---------------- build sorted token list (wave-aggregated atomics) ---------
__global__ void build_kernel(const int* __restrict__ routes,
                             const int* __restrict__ pad_off,
                             int* __restrict__ cursor,
                             int* __restrict__ sorted) {
  const int n = blockIdx.x * 256 + threadIdx.x;
  const int lane = threadIdx.x & 63;
  const int e = routes[n];
#pragma unroll
  for (int ex = 0; ex < NEXP; ++ex) {
    unsigned long long m = __ballot(e == ex);
    if (e == ex) {
      int leader = __ffsll(m) - 1;
      int rank = __popcll(m & ((1ull << lane) - 1ull));
      int b = 0;
      if (rank == 0) b = atomicAdd(&cursor[ex], (int)__popcll(m));
      b = __shfl(b, leader);
      sorted[pad_off[ex] + b + rank] = n;
    }
  }
}

// ---------------- grouped GEMM: 2-phase double-buffered, XCD-swizzled -------
// 1D grid nwg = NB * MAXTILES (divisible by 8). Work id: tile = w/NB (slow),
// nb = w%NB (fast) -> consecutive work ids share the A panel; bijective XCD
// swizzle makes panel-sharing neighbors land on the same XCD (T1).
// LDS: 2 buffers per operand; 16B-chunk XOR swizzle (chunk ^= row&7) applied
// on BOTH the per-lane global source and the ds_read_b128 address (rule #21).
// MODE 0: A = xb gathered via sorted, out = relu(acc+b1) -> bf16 h[pos][NDIM]
// MODE 1: A = h rows by pos,          out = acc+b2 -> fp32 out[token][NDIM]
template <int KDIM, int MODE, int NB>
__global__ __launch_bounds__(256) void gemm_moe(
    const unsigned short* __restrict__ A, const unsigned short* __restrict__ WT,
    const float* __restrict__ bias, const int* __restrict__ sorted,
    const int2* __restrict__ tile_table, void* __restrict__ Cout, int NDIM) {
  __shared__ short Al[2 * LDSZ];   // 2 x 16 KB
  __shared__ short Bl[2 * LDSZ];   // 2 x 16 KB

  // T1 bijective XCD swizzle (nwg % 8 == 0)
  const int nwg = NB * MAXTILES;
  const int bid = blockIdx.x;
  const int swz = (bid & 7) * (nwg >> 3) + (bid >> 3);
  int2 tt = tile_table[swz / NB];
  if (tt.x < 0) return;
  const int expert = tt.x;
  const int mbase = tt.y;
  const int n0 = (swz % NB) * BN;
  const int tid = threadIdx.x;
  const int lane = tid & 63;
  const int w = tid >> 6;

  // --- staging descriptors: wave w covers rows w*32..w*32+31 (4 issues of 8 rows)
  const int c = lane & 7;                 // 16B chunk within a 128B row
  const short* asrc[4];
  const short* bsrc[4];
  int dstoff[4];
#pragma unroll
  for (int i = 0; i < 4; ++i) {
    int row = (w * 4 + i) * 8 + (lane >> 3);
    int arow;
    if (MODE == 0) {
      int tok = sorted[mbase + row];
      arow = tok < 0 ? 0 : tok;           // pad rows: finite garbage, dropped later
    } else {
      arow = mbase + row;
    }
    int csw = (c ^ (row & 7)) * 8;        // pre-swizzled source chunk (elements)
    asrc[i] = (const short*)A + (size_t)arow * KDIM + csw;
    bsrc[i] = (const short*)WT + ((size_t)expert * NDIM + n0 + row) * KDIM + csw;
    dstoff[i] = (w * 4 + i) * 512;        // wave-uniform LDS base (shorts)
  }

  const int wm = (w >> 1) * 64, wn = (w & 1) * 64;
  const int fr = lane & 15, klo = lane >> 4;

  f32x4 acc[4][4];
#pragma unroll
  for (int m = 0; m < 4; ++m)
#pragma unroll
    for (int n = 0; n < 4; ++n) acc[m][n] = (f32x4){0.f, 0.f, 0.f, 0.f};

  constexpr int NT = KDIM / BK;
  // prologue: stage tile 0 into buffer 0
#pragma unroll
  for (int i = 0; i < 4; ++i) {
    gload_lds16(asrc[i], Al + dstoff[i]);
    gload_lds16(bsrc[i], Bl + dstoff[i]);
  }
  __syncthreads();

  int cur = 0;
  for (int t = 0; t < NT; ++t) {
    if (t + 1 < NT) {                      // stage next tile into other buffer
      int k0 = (t + 1) * BK;
      int nb = (cur ^ 1) * LDSZ;
#pragma unroll
      for (int i = 0; i < 4; ++i) {
        gload_lds16(asrc[i] + k0, Al + nb + dstoff[i]);
        gload_lds16(bsrc[i] + k0, Bl + nb + dstoff[i]);
      }
    }
    const short* Ab = Al + cur * LDSZ;
    const short* Bb = Bl + cur * LDSZ;
#pragma unroll
    for (int kk = 0; kk < 2; ++kk) {
      short8 a[4], b[4];
#pragma unroll
      for (int m = 0; m < 4; ++m) {
        int row = wm + m * 16 + fr;
        a[m] = *(const short8*)&Ab[row * 64 + (((kk * 4 + klo) ^ (row & 7)) << 3)];
      }
#pragma unroll
      for (int n = 0; n < 4; ++n) {
        int row = wn + n * 16 + fr;
        b[n] = *(const short8*)&Bb[row * 64 + (((kk * 4 + klo) ^ (row & 7)) << 3)];
      }
#pragma unroll
      for (int m = 0; m < 4; ++m)
#pragma unroll
        for (int n = 0; n < 4; ++n)
          acc[m][n] = __builtin_amdgcn_mfma_f32_16x16x32_bf16(a[m], b[n], acc[m][n], 0, 0, 0);
    }
    __syncthreads();   // drains vmcnt(0): next buffer ready; prev reads done
    cur ^= 1;
  }

  const int fq = lane >> 4;
#pragma unroll
  for (int m = 0; m < 4; ++m) {
    int rowl[4]; int tok[4];
#pragma unroll
    for (int r = 0; r < 4; ++r) {
      rowl[r] = mbase + wm + m * 16 + fq * 4 + r;
      if (MODE == 1) tok[r] = sorted[rowl[r]];
    }
#pragma unroll
    for (int n = 0; n < 4; ++n) {
      int col = n0 + wn + n * 16 + fr;
      float bv = bias[(size_t)expert * NDIM + col];
#pragma unroll
      for (int r = 0; r < 4; ++r) {
        float v = acc[m][n][r] + bv;
        if (MODE == 0) {
          v = fmaxf(v, 0.f);
          ((unsigned short*)Cout)[(size_t)rowl[r] * NDIM + col] = f2bf(v);
        } else {
          if (tok[r] >= 0) ((float*)Cout)[(size_t)tok[r] * NDIM + col] = v;
        }
      }
    }
  }
}

extern "C" void kernel_launch(void* const* d_in, const int* in_sizes, int n_in,
                              void* d_out, int out_size, void* d_ws, size_t ws_size,
                              hipStream_t stream) {
  const float* x  = (const float*)d_in[0];
  const float* Wr = (const float*)d_in[1];
  const float* br = (const float*)d_in[2];
  const float* W1 = (const float*)d_in[3];
  const float* b1 = (const float*)d_in[4];
  const float* W2 = (const float*)d_in[5];
  const float* b2 = (const float*)d_in[6];

  float* out_y      = (float*)d_out;                      // [N,O]
  float* out_probs  = out_y + (size_t)NTOK * OUTD;        // [N,E]
  float* out_counts = out_probs + (size_t)NTOK * NEXP;    // [E]

  char* ws = (char*)d_ws;
  unsigned short* xb   = (unsigned short*)(ws);                                    // 16 MB
  unsigned short* w1t  = (unsigned short*)(ws + 16777216ULL);                      // 32 MB
  unsigned short* w2t  = (unsigned short*)(ws + 16777216ULL + 33554432ULL);        // 32 MB
  unsigned short* hbuf = (unsigned short*)(ws + 16777216ULL + 2 * 33554432ULL);    // 36 MB
  char* p = ws + 16777216ULL + 2 * 33554432ULL + 37748736ULL;
  int* routes   = (int*)p; p += 32768;
  int* sorted   = (int*)p; p += (NTOK + NEXP * BM) * 4;   // 36864
  int* cursor   = (int*)p; p += 256;
  int* pad_off  = (int*)p; p += 256;
  int2* tt      = (int2*)p;

  hipMemsetAsync(sorted, 0xFF, (NTOK + NEXP * BM) * sizeof(int), stream);
  hipMemsetAsync(cursor, 0, 256, stream);

  transpose_convert_kernel<<<dim3(HID / 64, DIN / 64, NEXP), 256, 0, stream>>>(W1, w1t, DIN, HID);
  transpose_convert_kernel<<<dim3(OUTD / 64, HID / 64, NEXP), 256, 0, stream>>>(W2, w2t, HID, OUTD);
  fused_router_kernel<<<NTOK / 4, 256, 0, stream>>>(x, Wr, br, xb, out_probs, routes);
  hist_scan_kernel<<<1, 256, 0, stream>>>(routes, pad_off, tt, out_counts);
  build_kernel<<<NTOK / 256, 256, 0, stream>>>(routes, pad_off, cursor, sorted);
  gemm_moe<DIN, 0, HID / BN><<<(HID / BN) * MAXTILES, 256, 0, stream>>>(
      xb, w1t, b1, sorted, tt, hbuf, HID);
  gemm_moe<HID, 1, OUTD / BN><<<(OUTD / BN) * MAXTILES, 256, 0, stream>>>(
      hbuf, w2t, b2, sorted, tt, out_y, OUTD);
}

// Round 5
// 218.794 us; speedup vs baseline: 1.1360x; 1.1360x over previous
//
#include <hip/hip_runtime.h>
#include <hip/hip_bf16.h>

#define NTOK 8192
#define DIN  1024
#define HID  2048
#define OUTD 1024
#define NEXP 8
#define BM 128
#define BN 128
#define BK 32
#define MAXTILES (NTOK / BM + NEXP)   // 72
#define LDSZ (BM * BK)                // shorts per operand buffer (4096 = 8 KB)

typedef short short8 __attribute__((ext_vector_type(8)));
typedef float f32x4 __attribute__((ext_vector_type(4)));

static __device__ __forceinline__ unsigned short f2bf(float f) {
  union { __hip_bfloat16 b; unsigned short u; } cv;
  cv.b = __float2bfloat16(f);
  return cv.u;
}

static __device__ __forceinline__ void gload_lds16(const void* g, void* l) {
  __builtin_amdgcn_global_load_lds(
      (const __attribute__((address_space(1))) void*)g,
      (__attribute__((address_space(3))) void*)l, 16, 0, 0);
}

// ---------------- prep: W [E][R][C] fp32 -> WT [E][C][R] bf16 ----------------
// 64x64 tiles, float4 loads / ushort4 stores.
__global__ __launch_bounds__(256) void transpose_convert_kernel(
    const float* __restrict__ W, unsigned short* __restrict__ WT, int R, int C) {
  __shared__ float tile[64][65];
  const int e = blockIdx.z;
  const int c0 = blockIdx.x * 64, r0 = blockIdx.y * 64;
  const int lr = threadIdx.x >> 4;    // 0..15
  const int fc = threadIdx.x & 15;    // float4 column
  const float* Wp = W + ((size_t)e * R + r0) * C + c0;
#pragma unroll
  for (int i = 0; i < 4; ++i) {
    int r = lr + i * 16;
    float4 v = *(const float4*)(Wp + (size_t)r * C + fc * 4);
    tile[r][fc * 4 + 0] = v.x; tile[r][fc * 4 + 1] = v.y;
    tile[r][fc * 4 + 2] = v.z; tile[r][fc * 4 + 3] = v.w;
  }
  __syncthreads();
  unsigned short* Op = WT + ((size_t)e * C + c0) * R + r0;
#pragma unroll
  for (int i = 0; i < 4; ++i) {
    int cc = lr + i * 16;             // output row = source col
    int rb = fc * 4;                  // 4 source rows
    ushort4 o = { f2bf(tile[rb + 0][cc]), f2bf(tile[rb + 1][cc]),
                  f2bf(tile[rb + 2][cc]), f2bf(tile[rb + 3][cc]) };
    *(ushort4*)(Op + (size_t)cc * R + rb) = o;
  }
}

// ---------------- fused: x fp32 -> bf16  +  router (fp32, NO atomics) ------
__global__ __launch_bounds__(256) void fused_router_kernel(
    const float* __restrict__ x, const float* __restrict__ Wr,
    const float* __restrict__ br, unsigned short* __restrict__ xb,
    float* __restrict__ probs_out, int* __restrict__ routes) {
  __shared__ float WrL[NEXP][DIN];   // transposed router weights, 32 KB
  const int tid = threadIdx.x;
#pragma unroll
  for (int rr = 0; rr < 4; ++rr) {
    int row = tid * 4 + rr;
    float4 w0 = *(const float4*)(Wr + (size_t)row * NEXP);
    float4 w1 = *(const float4*)(Wr + (size_t)row * NEXP + 4);
    WrL[0][row] = w0.x; WrL[1][row] = w0.y; WrL[2][row] = w0.z; WrL[3][row] = w0.w;
    WrL[4][row] = w1.x; WrL[5][row] = w1.y; WrL[6][row] = w1.z; WrL[7][row] = w1.w;
  }
  __syncthreads();

  const int lane = tid & 63;
  const int n = blockIdx.x * 4 + (tid >> 6);
  const float4* xr = (const float4*)(x + (size_t)n * DIN);
  ushort4* xo = (ushort4*)(xb + (size_t)n * DIN);
  float acc[NEXP];
#pragma unroll
  for (int e = 0; e < NEXP; ++e) acc[e] = 0.f;
#pragma unroll
  for (int j = 0; j < 4; ++j) {
    int idx = j * 64 + lane;            // coalesced: 64 consecutive float4
    float4 xv = xr[idx];
    ushort4 o = { f2bf(xv.x), f2bf(xv.y), f2bf(xv.z), f2bf(xv.w) };
    xo[idx] = o;
    int r0 = idx * 4;
#pragma unroll
    for (int e = 0; e < NEXP; ++e) {
      float4 wv = *(const float4*)&WrL[e][r0];
      acc[e] += xv.x * wv.x + xv.y * wv.y + xv.z * wv.z + xv.w * wv.w;
    }
  }
#pragma unroll
  for (int m = 1; m < 64; m <<= 1)
#pragma unroll
    for (int e = 0; e < NEXP; ++e) acc[e] += __shfl_xor(acc[e], m);

  if (lane == 0) {
    float lg[NEXP], p[NEXP];
    float mx = -1e30f;
#pragma unroll
    for (int e = 0; e < NEXP; ++e) { lg[e] = acc[e] + br[e]; mx = fmaxf(mx, lg[e]); }
    float s = 0.f;
#pragma unroll
    for (int e = 0; e < NEXP; ++e) { p[e] = expf(lg[e] - mx); s += p[e]; }
    float inv = 1.f / s;
    int best = 0; float bp = -1.f;
#pragma unroll
    for (int e = 0; e < NEXP; ++e) {
      p[e] *= inv;
      probs_out[(size_t)n * NEXP + e] = p[e];
      if (p[e] > bp) { bp = p[e]; best = e; }   // strict > : first-index tie-break
    }
    routes[n] = best;
  }
}

// ---------------- histogram + scan (single block, no atomics) ----------------
__global__ __launch_bounds__(256) void hist_scan_kernel(
    const int* __restrict__ routes, int* __restrict__ pad_off,
    int2* __restrict__ tile_table, float* __restrict__ counts_out) {
  __shared__ int wsum[4][NEXP];
  const int tid = threadIdx.x;
  const int lane = tid & 63, w = tid >> 6;
  int cnt[NEXP];
#pragma unroll
  for (int e = 0; e < NEXP; ++e) cnt[e] = 0;
#pragma unroll
  for (int j = 0; j < 8; ++j) {
    int4 r4 = ((const int4*)routes)[tid + 256 * j];
    int rr[4] = {r4.x, r4.y, r4.z, r4.w};
#pragma unroll
    for (int i = 0; i < 4; ++i)
#pragma unroll
      for (int e = 0; e < NEXP; ++e) cnt[e] += (rr[i] == e);  // no runtime idx -> regs
  }
#pragma unroll
  for (int m = 1; m < 64; m <<= 1)
#pragma unroll
    for (int e = 0; e < NEXP; ++e) cnt[e] += __shfl_xor(cnt[e], m);
  if (lane == 0)
#pragma unroll
    for (int e = 0; e < NEXP; ++e) wsum[w][e] = cnt[e];
  __syncthreads();
  if (tid == 0) {
    int off = 0, t = 0;
    for (int e = 0; e < NEXP; ++e) {
      int c = wsum[0][e] + wsum[1][e] + wsum[2][e] + wsum[3][e];
      pad_off[e] = off;
      counts_out[e] = (float)c;
      int tiles = (c + BM - 1) / BM;
      for (int i = 0; i < tiles; ++i) { tile_table[t] = make_int2(e, off + i * BM); ++t; }
      off += tiles * BM;
    }
    for (; t < MAXTILES; ++t) tile_table[t] = make_int2(-1, 0);
  }
}

// ---------------- build sorted token list (wave-aggregated atomics) ---------
__global__ void build_kernel(const int* __restrict__ routes,
                             const int* __restrict__ pad_off,
                             int* __restrict__ cursor,
                             int* __restrict__ sorted) {
  const int n = blockIdx.x * 256 + threadIdx.x;
  const int lane = threadIdx.x & 63;
  const int e = routes[n];
#pragma unroll
  for (int ex = 0; ex < NEXP; ++ex) {
    unsigned long long m = __ballot(e == ex);
    if (e == ex) {
      int leader = __ffsll(m) - 1;
      int rank = __popcll(m & ((1ull << lane) - 1ull));
      int b = 0;
      if (rank == 0) b = atomicAdd(&cursor[ex], (int)__popcll(m));
      b = __shfl(b, leader);
      sorted[pad_off[ex] + b + rank] = n;
    }
  }
}

// ---------------- grouped GEMM: 2-phase dbuf, BK=32 (32KB LDS), XCD swizzle -
// 1D grid nwg = NB * MAXTILES (divisible by 8). tile = w/NB (slow), nb = w%NB
// (fast) -> consecutive work ids share the A panel; bijective XCD swizzle.
// LDS rows are 64B (4 chunks of 16B); chunk XOR swizzle (c ^= row&3) applied
// on BOTH the per-lane global source and the ds_read_b128 address (rule #21).
// MODE 0: A = xb gathered via sorted, out = relu(acc+b1) -> bf16 h[pos][NDIM]
// MODE 1: A = h rows by pos,          out = acc+b2 -> fp32 out[token][NDIM]
template <int KDIM, int MODE, int NB>
__global__ __launch_bounds__(256) void gemm_moe(
    const unsigned short* __restrict__ A, const unsigned short* __restrict__ WT,
    const float* __restrict__ bias, const int* __restrict__ sorted,
    const int2* __restrict__ tile_table, void* __restrict__ Cout, int NDIM) {
  __shared__ short Al[2 * LDSZ];   // 2 x 8 KB
  __shared__ short Bl[2 * LDSZ];   // 2 x 8 KB

  // T1 bijective XCD swizzle (nwg % 8 == 0)
  const int nwg = NB * MAXTILES;
  const int bid = blockIdx.x;
  const int swz = (bid & 7) * (nwg >> 3) + (bid >> 3);
  int2 tt = tile_table[swz / NB];
  if (tt.x < 0) return;
  const int expert = tt.x;
  const int mbase = tt.y;
  const int n0 = (swz % NB) * BN;
  const int tid = threadIdx.x;
  const int lane = tid & 63;
  const int w = tid >> 6;

  // --- staging: wave w covers rows w*32..w*32+31 (2 issues x 16 rows each)
  const int c = lane & 3;                 // 16B chunk within a 64B row
  const short* asrc[2];
  const short* bsrc[2];
  int dstoff[2];
#pragma unroll
  for (int i = 0; i < 2; ++i) {
    int row = w * 32 + i * 16 + (lane >> 2);
    int arow;
    if (MODE == 0) {
      int tok = sorted[mbase + row];
      arow = tok < 0 ? 0 : tok;           // pad rows: finite garbage, dropped later
    } else {
      arow = mbase + row;
    }
    int csw = (c ^ (row & 3)) * 8;        // pre-swizzled source chunk (shorts)
    asrc[i] = (const short*)A + (size_t)arow * KDIM + csw;
    bsrc[i] = (const short*)WT + ((size_t)expert * NDIM + n0 + row) * KDIM + csw;
    dstoff[i] = (w * 32 + i * 16) * BK;   // wave-uniform LDS base (shorts)
  }

  const int wm = (w >> 1) * 64, wn = (w & 1) * 64;
  const int fr = lane & 15, klo = lane >> 4;

  f32x4 acc[4][4];
#pragma unroll
  for (int m = 0; m < 4; ++m)
#pragma unroll
    for (int n = 0; n < 4; ++n) acc[m][n] = (f32x4){0.f, 0.f, 0.f, 0.f};

  constexpr int NT = KDIM / BK;
  // prologue: stage tile 0 into buffer 0
#pragma unroll
  for (int i = 0; i < 2; ++i) {
    gload_lds16(asrc[i], Al + dstoff[i]);
    gload_lds16(bsrc[i], Bl + dstoff[i]);
  }
  __syncthreads();

  int cur = 0;
  for (int t = 0; t < NT; ++t) {
    if (t + 1 < NT) {                      // stage next tile into other buffer
      int k0 = (t + 1) * BK;
      int nb = (cur ^ 1) * LDSZ;
#pragma unroll
      for (int i = 0; i < 2; ++i) {
        gload_lds16(asrc[i] + k0, Al + nb + dstoff[i]);
        gload_lds16(bsrc[i] + k0, Bl + nb + dstoff[i]);
      }
    }
    const short* Ab = Al + cur * LDSZ;
    const short* Bb = Bl + cur * LDSZ;
    short8 a[4], b[4];
#pragma unroll
    for (int m = 0; m < 4; ++m) {
      int row = wm + m * 16 + fr;
      a[m] = *(const short8*)&Ab[row * BK + ((klo ^ (row & 3)) << 3)];
    }
#pragma unroll
    for (int n = 0; n < 4; ++n) {
      int row = wn + n * 16 + fr;
      b[n] = *(const short8*)&Bb[row * BK + ((klo ^ (row & 3)) << 3)];
    }
#pragma unroll
    for (int m = 0; m < 4; ++m)
#pragma unroll
      for (int n = 0; n < 4; ++n)
        acc[m][n] = __builtin_amdgcn_mfma_f32_16x16x32_bf16(a[m], b[n], acc[m][n], 0, 0, 0);
    __syncthreads();   // drains vmcnt(0): next buffer ready; prev reads done
    cur ^= 1;
  }

  const int fq = lane >> 4;
#pragma unroll
  for (int m = 0; m < 4; ++m) {
    int rowl[4]; int tok[4];
#pragma unroll
    for (int r = 0; r < 4; ++r) {
      rowl[r] = mbase + wm + m * 16 + fq * 4 + r;
      if (MODE == 1) tok[r] = sorted[rowl[r]];
    }
#pragma unroll
    for (int n = 0; n < 4; ++n) {
      int col = n0 + wn + n * 16 + fr;
      float bv = bias[(size_t)expert * NDIM + col];
#pragma unroll
      for (int r = 0; r < 4; ++r) {
        float v = acc[m][n][r] + bv;
        if (MODE == 0) {
          v = fmaxf(v, 0.f);
          ((unsigned short*)Cout)[(size_t)rowl[r] * NDIM + col] = f2bf(v);
        } else {
          if (tok[r] >= 0) ((float*)Cout)[(size_t)tok[r] * NDIM + col] = v;
        }
      }
    }
  }
}

extern "C" void kernel_launch(void* const* d_in, const int* in_sizes, int n_in,
                              void* d_out, int out_size, void* d_ws, size_t ws_size,
                              hipStream_t stream) {
  const float* x  = (const float*)d_in[0];
  const float* Wr = (const float*)d_in[1];
  const float* br = (const float*)d_in[2];
  const float* W1 = (const float*)d_in[3];
  const float* b1 = (const float*)d_in[4];
  const float* W2 = (const float*)d_in[5];
  const float* b2 = (const float*)d_in[6];

  float* out_y      = (float*)d_out;                      // [N,O]
  float* out_probs  = out_y + (size_t)NTOK * OUTD;        // [N,E]
  float* out_counts = out_probs + (size_t)NTOK * NEXP;    // [E]

  char* ws = (char*)d_ws;
  unsigned short* xb   = (unsigned short*)(ws);                                    // 16 MB
  unsigned short* w1t  = (unsigned short*)(ws + 16777216ULL);                      // 32 MB
  unsigned short* w2t  = (unsigned short*)(ws + 16777216ULL + 33554432ULL);        // 32 MB
  unsigned short* hbuf = (unsigned short*)(ws + 16777216ULL + 2 * 33554432ULL);    // 36 MB
  char* p = ws + 16777216ULL + 2 * 33554432ULL + 37748736ULL;
  int* routes   = (int*)p; p += 32768;
  int* sorted   = (int*)p; p += (NTOK + NEXP * BM) * 4;   // 36864
  int* cursor   = (int*)p; p += 256;
  int* pad_off  = (int*)p; p += 256;
  int2* tt      = (int2*)p;

  hipMemsetAsync(sorted, 0xFF, (NTOK + NEXP * BM) * sizeof(int), stream);
  hipMemsetAsync(cursor, 0, 256, stream);

  transpose_convert_kernel<<<dim3(HID / 64, DIN / 64, NEXP), 256, 0, stream>>>(W1, w1t, DIN, HID);
  transpose_convert_kernel<<<dim3(OUTD / 64, HID / 64, NEXP), 256, 0, stream>>>(W2, w2t, HID, OUTD);
  fused_router_kernel<<<NTOK / 4, 256, 0, stream>>>(x, Wr, br, xb, out_probs, routes);
  hist_scan_kernel<<<1, 256, 0, stream>>>(routes, pad_off, tt, out_counts);
  build_kernel<<<NTOK / 256, 256, 0, stream>>>(routes, pad_off, cursor, sorted);
  gemm_moe<DIN, 0, HID / BN><<<(HID / BN) * MAXTILES, 256, 0, stream>>>(
      xb, w1t, b1, sorted, tt, hbuf, HID);
  gemm_moe<HID, 1, OUTD / BN><<<(OUTD / BN) * MAXTILES, 256, 0, stream>>>(
      hbuf, w2t, b2, sorted, tt, out_y, OUTD);
}